// Round 16
// baseline (88.383 us; speedup 1.0000x reference)
//
#include <hip/hip_runtime.h>
#include <stdint.h>

#define NN 8192
#define DD 512
#define BK 64             // bf16 elements per K-step = 128 B rows in LDS
#define NKT (DD / BK)     // 8
#define NB 64             // 128-wide col-block count
#define NPAIRS 2080       // NB*(NB+1)/2 upper-triangular 128x128 pairs
#define GRID 4160         // 2 x 64-row halves per pair

typedef short s16x8 __attribute__((ext_vector_type(8)));
typedef float f32x4 __attribute__((ext_vector_type(4)));

template <bool B> struct BoolC { static constexpr bool value = B; };

static __device__ __forceinline__ short f2bf(float x) {
  union { float f; uint32_t u; } c; c.f = x;
  uint32_t r = c.u + 0x7fffu + ((c.u >> 16) & 1u);   // RNE
  return (short)(r >> 16);
}

static __device__ __forceinline__ int tri_off(int b) {
  return b * NB - (b * (b - 1)) / 2;
}

static __device__ __forceinline__ void gload16(const void* g, void* l) {
  __builtin_amdgcn_global_load_lds(
      (const __attribute__((address_space(1))) void*)g,
      (__attribute__((address_space(3))) void*)l, 16, 0, 0);
}

// 4 waves/block, one row per wave: fp32 -> bf16, sq-norm, init reductions.
__global__ __launch_bounds__(256) void prep_kernel(
    const float* __restrict__ f, short* __restrict__ fb,
    float* __restrict__ sqn, float* __restrict__ pmax,
    float* __restrict__ nmin) {
  int wid = threadIdx.x >> 6, lane = threadIdx.x & 63;
  int row = blockIdx.x * 4 + wid;
  const f32x4* src = (const f32x4*)(f + (size_t)row * DD);
  f32x4 v0 = __builtin_nontemporal_load(&src[lane * 2]);
  f32x4 v1 = __builtin_nontemporal_load(&src[lane * 2 + 1]);
  float s = v0[0]*v0[0] + v0[1]*v0[1] + v0[2]*v0[2] + v0[3]*v0[3]
          + v1[0]*v1[0] + v1[1]*v1[1] + v1[2]*v1[2] + v1[3]*v1[3];
  s16x8 o;
  o[0]=f2bf(v0[0]); o[1]=f2bf(v0[1]); o[2]=f2bf(v0[2]); o[3]=f2bf(v0[3]);
  o[4]=f2bf(v1[0]); o[5]=f2bf(v1[1]); o[6]=f2bf(v1[2]); o[7]=f2bf(v1[3]);
  *(s16x8*)&fb[(size_t)row * DD + lane * 8] = o;
  #pragma unroll
  for (int m = 1; m < 64; m <<= 1) s += __shfl_xor(s, m);
  if (lane == 0) {
    sqn[row] = s;
    pmax[row] = 0.f;
    nmin[row] = __int_as_float(0x7f800000);   // +inf
  }
}

// 64x128 tiles of F*F^T (two 64-row halves per upper-tri 128x128 pair).
// vs R14 (59.0 us): acc 64 -> 32 VGPRs per thread => (256,4) fits the
// 128-VGPR unified budget WITHOUT spill (R6's failure mode cleared by
// arithmetic, not hope) -> 4 independent blocks/CU instead of 3. R15
// proved independent-block overlap is the scarce resource; this buys
// +33% of it. A/B both LDS-staged (R15's A-direct regressed), same
// both-sides swizzle, same R14 scatter epilogue in squared space.
__global__ __launch_bounds__(256, 4) void tile_kernel(
    const short* __restrict__ fb, const float* __restrict__ sqn,
    const int* __restrict__ lab,
    float* __restrict__ pmax, float* __restrict__ nmin) {
  __shared__ __align__(16) char smem[30208];
  short* Bs     = (short*)smem;              // [0, 16384)   128 rows x 64
  short* As     = (short*)(smem + 16384);    // [16384, 24576)  64 rows x 64
  float* s_sq_r = (float*)(smem + 24576);    // 256 B (64 rows)
  float* s_sq_c = (float*)(smem + 24832);    // 512 B (128 cols)
  int*   s_lb_r = (int*)(smem + 25344);      // 256 B
  int*   s_lb_c = (int*)(smem + 25600);      // 512 B (ends 26112)
  float* colP   = (float*)(smem + 26112);    // [128][4]  2 KB
  float* colN   = (float*)(smem + 28160);    // [128][4]  2 KB (ends 30208)
  // epilogue aliases onto Bs (all Bs reads complete before last mid-barrier):
  float* rowP   = (float*)smem;              // [64][18]  [0, 4608)
  float* rowN   = (float*)(smem + 4608);     // [64][18]  [4608, 9216)

  // XCD swizzle (4160 % 8 == 0, bijective) -> pair + half decode
  int L = blockIdx.x;
  int t = (L & 7) * (GRID / 8) + (L >> 3);
  int P = t >> 1, half = t & 1;
  int bi = (int)((129.0f - sqrtf(16641.0f - 8.0f * (float)P)) * 0.5f);
  if (bi < 0) bi = 0;
  while (bi > 0 && tri_off(bi) > P) --bi;
  while (tri_off(bi + 1) <= P) ++bi;
  int bj = bi + (P - tri_off(bi));
  int brow = bi * 128 + half * 64, bcol = bj * 128;
  bool diag_blk = (bi == bj);

  int tid = threadIdx.x;
  int wid = tid >> 6, lane = tid & 63;
  int hi = lane >> 4, lo = lane & 15;

  if (tid < 64) {
    s_sq_r[tid] = sqn[brow + tid];
    s_lb_r[tid] = lab[brow + tid];
  }
  if (tid < 128) {
    s_sq_c[tid] = sqn[bcol + tid];
    s_lb_c[tid] = lab[bcol + tid];
  }

  f32x4 acc[8];
  #pragma unroll
  for (int b = 0; b < 8; ++b) acc[b] = (f32x4)(0.f);

  // staging lane constants (8-row segments; both-sides swizzle):
  // LDS[row][p] = G[row][p ^ (row&7)], linear dest per gload16 instruction
  int lrow = lane >> 3;
  int lchunk = (lane & 7) ^ lrow;
  size_t lane_goff = (size_t)lrow * DD + lchunk * 8;   // shorts
  const short* gA = fb + (size_t)brow * DD + lane_goff;
  const short* gB = fb + (size_t)bcol * DD + lane_goff;

  // read-side swizzled chunk: want G[row][C], C = ks*4+hi; row&7 == lo&7
  int cs0 = hi ^ (lo & 7);          // ks=0
  int cs1 = cs0 ^ 4;                // ks=1
  int a0r = wid * 16 + lo;          // this wave's A row

#define STAGE(ktn) do {                                               \
    int kb_ = (ktn) * BK;                                             \
    _Pragma("unroll")                                                 \
    for (int i_ = 0; i_ < 4; ++i_) {                                  \
      int seg_ = wid * 4 + i_;                                        \
      gload16(gB + (size_t)seg_ * 8 * DD + kb_, &Bs[seg_ * 512]);     \
    }                                                                 \
    _Pragma("unroll")                                                 \
    for (int i_ = 0; i_ < 2; ++i_) {                                  \
      int seg_ = wid * 2 + i_;                                        \
      gload16(gA + (size_t)seg_ * 8 * DD + kb_, &As[seg_ * 512]);     \
    }                                                                 \
  } while (0)

  STAGE(0);   // prologue

  for (int kt = 0; kt < NKT; ++kt) {
    __syncthreads();   // drains STAGE(kt) (vmcnt0) + prior reads done
    // ks=0 fragments + MFMA
    s16x8 a0 = *(const s16x8*)&As[a0r * 64 + cs0 * 8];
    s16x8 bfr[8];
    #pragma unroll
    for (int fc = 0; fc < 8; ++fc)
      bfr[fc] = *(const s16x8*)&Bs[(fc * 16 + lo) * 64 + cs0 * 8];
    #pragma unroll
    for (int fc = 0; fc < 8; ++fc)
      acc[fc] = __builtin_amdgcn_mfma_f32_16x16x32_bf16(a0, bfr[fc], acc[fc], 0, 0, 0);
    // ks=1 fragments
    s16x8 c0 = *(const s16x8*)&As[a0r * 64 + cs1 * 8];
    s16x8 dfr[8];
    #pragma unroll
    for (int fc = 0; fc < 8; ++fc)
      dfr[fc] = *(const s16x8*)&Bs[(fc * 16 + lo) * 64 + cs1 * 8];
    __syncthreads();   // all waves done reading (lgkm; vmcnt already 0)
    if (kt + 1 < NKT) STAGE(kt + 1);       // overwrite OK; drains next iter
    __builtin_amdgcn_sched_barrier(0);     // keep STAGE above the MFMA cluster
    #pragma unroll
    for (int fc = 0; fc < 8; ++fc)
      acc[fc] = __builtin_amdgcn_mfma_f32_16x16x32_bf16(c0, dfr[fc], acc[fc], 0, 0, 0);
  }
#undef STAGE
  // kt=NKT-1's mid __syncthreads guarantees all As/Bs reads done ->
  // rowP/rowN aliasing onto Bs is safe.

  // Epilogue: SQUARED distances (unclamped; finalize clamps) + masked
  // max/min, templated on diagonal. Row partials scatter to LDS (R14).
  const float FINF = __int_as_float(0x7f800000);
  auto epilogue = [&](auto diag_c) {
    constexpr bool DIAG = decltype(diag_c)::value;
    float cvp[8], cvn[8];
    #pragma unroll
    for (int fc = 0; fc < 8; ++fc) { cvp[fc] = 0.f; cvn[fc] = FINF; }

    #pragma unroll
    for (int rg = 0; rg < 4; ++rg) {
      int rt = wid * 16 + hi * 4 + rg;
      float sqi = s_sq_r[rt];
      int   li  = s_lb_r[rt];
      float vp = 0.f, vn = FINF;
      #pragma unroll
      for (int fc = 0; fc < 8; ++fc) {
        int ct = fc * 16 + lo;
        float g = acc[fc][rg];
        float v = sqi + s_sq_c[ct] - 2.0f * g;            // squared dist (unclamped)
        if constexpr (DIAG) { if (brow + rt == bcol + ct) v = 0.f; }  // diagonal
        bool same = (li == s_lb_c[ct]);
        if (same) {
          vp = fmaxf(vp, v);
          cvp[fc] = fmaxf(cvp[fc], v);
        } else {
          vn = fminf(vn, v);
          cvn[fc] = fminf(cvn[fc], v);
        }
      }
      // scatter this (row, lo) partial; reduce after the barrier
      rowP[rt * 18 + lo] = vp;
      rowN[rt * 18 + lo] = vn;
    }
    // column-side: combine across hi groups in-wave, write [ct][wid] partials
    #pragma unroll
    for (int fc = 0; fc < 8; ++fc) {
      #pragma unroll
      for (int m = 16; m < 64; m <<= 1) {
        cvp[fc] = fmaxf(cvp[fc], __shfl_xor(cvp[fc], m));
        cvn[fc] = fminf(cvn[fc], __shfl_xor(cvn[fc], m));
      }
      if (hi == 0) {
        int ct = fc * 16 + lo;
        colP[ct * 4 + wid] = cvp[fc];
        colN[ct * 4 + wid] = cvn[fc];
      }
    }
    __syncthreads();
    if (tid < 64) {
      // row reduce: 16 contiguous floats, 4 x b128
      f32x4 p0 = *(const f32x4*)&rowP[tid * 18 + 0];
      f32x4 p1 = *(const f32x4*)&rowP[tid * 18 + 4];
      f32x4 p2 = *(const f32x4*)&rowP[tid * 18 + 8];
      f32x4 p3 = *(const f32x4*)&rowP[tid * 18 + 12];
      f32x4 n0 = *(const f32x4*)&rowN[tid * 18 + 0];
      f32x4 n1 = *(const f32x4*)&rowN[tid * 18 + 4];
      f32x4 n2 = *(const f32x4*)&rowN[tid * 18 + 8];
      f32x4 n3 = *(const f32x4*)&rowN[tid * 18 + 12];
      f32x4 pm = __builtin_elementwise_max(__builtin_elementwise_max(p0, p1),
                                           __builtin_elementwise_max(p2, p3));
      f32x4 nm = __builtin_elementwise_min(__builtin_elementwise_min(n0, n1),
                                           __builtin_elementwise_min(n2, n3));
      float p = fmaxf(fmaxf(pm[0], pm[1]), fmaxf(pm[2], pm[3]));
      float n = fminf(fminf(nm[0], nm[1]), fminf(nm[2], nm[3]));
      int gi = brow + tid;
      atomicMax((int*)&pmax[gi], __float_as_int(p));
      atomicMin((int*)&nmin[gi], __float_as_int(n));
    }
    if (tid < 128) {
      // col reduce: 4 partials, 1 x b128 each
      f32x4 cp = *(const f32x4*)&colP[tid * 4];
      f32x4 cn = *(const f32x4*)&colN[tid * 4];
      float pc = fmaxf(fmaxf(cp[0], cp[1]), fmaxf(cp[2], cp[3]));
      float nc = fminf(fminf(cn[0], cn[1]), fminf(cn[2], cn[3]));
      int gj = bcol + tid;
      atomicMax((int*)&pmax[gj], __float_as_int(pc));
      atomicMin((int*)&nmin[gj], __float_as_int(nc));
    }
  };
  if (diag_blk) epilogue(BoolC<true>{});
  else          epilogue(BoolC<false>{});
}

// Atomic-sign correctness: pmax candidates >= 0 (0-init) -> int-atomicMax
// order-correct. nmin candidates may be tiny-negative (cancellation);
// int-atomicMin ranks negatives below non-negatives, finalize clamps the
// winner to 0 == reference's clamped min.
__global__ __launch_bounds__(256) void finalize_kernel(
    const float* __restrict__ pmax, const float* __restrict__ nmin,
    float* __restrict__ out) {
  int i = blockIdx.x * blockDim.x + threadIdx.x;
  if (i < NN) {
    const float FINF = __int_as_float(0x7f800000);
    float p = fmaxf(pmax[i], 0.f);
    float n = nmin[i];
    if (n == FINF) n = p;       // empty-negative fallback: axis_max == pmax
    n = fmaxf(n, 0.f);
    out[2 * i]     = sqrtf(p);
    out[2 * i + 1] = sqrtf(n);
  }
}

extern "C" void kernel_launch(void* const* d_in, const int* in_sizes, int n_in,
                              void* d_out, int out_size, void* d_ws, size_t ws_size,
                              hipStream_t stream) {
  const float* feat = (const float*)d_in[0];
  const int*   lab  = (const int*)d_in[1];
  float* out = (float*)d_out;

  char* ws = (char*)d_ws;
  short* fb   = (short*)ws;                                  // 8192*512*2 = 8388608 B
  float* sqn  = (float*)(ws + 8388608);                      // 32768 B
  float* pmax = (float*)(ws + 8388608 + 32768);              // 32768 B
  float* nmin = (float*)(ws + 8388608 + 2 * 32768);          // 32768 B

  prep_kernel<<<NN / 4, 256, 0, stream>>>(feat, fb, sqn, pmax, nmin);
  tile_kernel<<<GRID, 256, 0, stream>>>(fb, sqn, lab, pmax, nmin);
  finalize_kernel<<<(NN + 255) / 256, 256, 0, stream>>>(pmax, nmin, out);
}

// Round 17
// 74.726 us; speedup vs baseline: 1.1828x; 1.1828x over previous
//
#include <hip/hip_runtime.h>
#include <stdint.h>

#define NN 8192
#define DD 512
#define BM 128
#define BK 64             // bf16 elements per K-step = 128 B rows in LDS
#define NKT (DD / BK)     // 8
#define NB 64             // NN / BM
#define NTILES 2080       // NB*(NB+1)/2 upper-triangular tiles

typedef short s16x8 __attribute__((ext_vector_type(8)));
typedef float f32x4 __attribute__((ext_vector_type(4)));

template <bool B> struct BoolC { static constexpr bool value = B; };

static __device__ __forceinline__ short f2bf(float x) {
  union { float f; uint32_t u; } c; c.f = x;
  uint32_t r = c.u + 0x7fffu + ((c.u >> 16) & 1u);   // RNE
  return (short)(r >> 16);
}

static __device__ __forceinline__ int tri_off(int b) {
  return b * NB - (b * (b - 1)) / 2;
}

static __device__ __forceinline__ void gload16(const void* g, void* l) {
  __builtin_amdgcn_global_load_lds(
      (const __attribute__((address_space(1))) void*)g,
      (__attribute__((address_space(3))) void*)l, 16, 0, 0);
}

// 4 waves/block, one row per wave: fp32 -> bf16, sq-norm, init reductions.
__global__ __launch_bounds__(256) void prep_kernel(
    const float* __restrict__ f, short* __restrict__ fb,
    float* __restrict__ sqn, float* __restrict__ pmax,
    float* __restrict__ nmin) {
  int wid = threadIdx.x >> 6, lane = threadIdx.x & 63;
  int row = blockIdx.x * 4 + wid;
  const f32x4* src = (const f32x4*)(f + (size_t)row * DD);
  f32x4 v0 = __builtin_nontemporal_load(&src[lane * 2]);
  f32x4 v1 = __builtin_nontemporal_load(&src[lane * 2 + 1]);
  float s = v0[0]*v0[0] + v0[1]*v0[1] + v0[2]*v0[2] + v0[3]*v0[3]
          + v1[0]*v1[0] + v1[1]*v1[1] + v1[2]*v1[2] + v1[3]*v1[3];
  s16x8 o;
  o[0]=f2bf(v0[0]); o[1]=f2bf(v0[1]); o[2]=f2bf(v0[2]); o[3]=f2bf(v0[3]);
  o[4]=f2bf(v1[0]); o[5]=f2bf(v1[1]); o[6]=f2bf(v1[2]); o[7]=f2bf(v1[3]);
  *(s16x8*)&fb[(size_t)row * DD + lane * 8] = o;
  #pragma unroll
  for (int m = 1; m < 64; m <<= 1) s += __shfl_xor(s, m);
  if (lane == 0) {
    sqn[row] = s;
    pmax[row] = 0.f;
    nmin[row] = __int_as_float(0x7f800000);   // +inf
  }
}

// Upper-triangular 128x128 tiles of F*F^T via bf16 MFMA + global_load_lds.
// BEST VERIFIED (R14: tile 58.9-59.1 us): both-sides swizzle 0-conflict
// staging, (256,3) no-spill, squared-space epilogue, no rmax, deferred
// clamp, LDS scatter-transpose row reduce. 16 rounds of ledger:
//   deletion wins: squared-space(-12us) rmax(-10us) clamp(-1us)
//   falsified: dbuf(R3,R10), 256^2 8-phase(R4-R6: register wall),
//              hoists(R7), reorder(R11: null), A-direct(R15: -12us),
//              64x128(R16: -13us, staging dilution)
// Structure sits at the 2-barrier regime's measured MfmaUtil cap (~23-25%).
__global__ __launch_bounds__(256, 3) void tile_kernel(
    const short* __restrict__ fb, const float* __restrict__ sqn,
    const int* __restrict__ lab,
    float* __restrict__ pmax, float* __restrict__ nmin) {
  __shared__ __align__(16) char smem[38912];
  short* As     = (short*)smem;              // [0, 16384)
  short* Bs     = (short*)(smem + 16384);    // [16384, 32768)
  float* s_sq_r = (float*)(smem + 32768);    // 512 B
  float* s_sq_c = (float*)(smem + 33280);    // 512 B
  int*   s_lb_r = (int*)(smem + 33792);      // 512 B
  int*   s_lb_c = (int*)(smem + 34304);      // 512 B  (ends 34816)
  float* colP   = (float*)(smem + 34816);    // [128][4]  2 KB
  float* colN   = (float*)(smem + 36864);    // [128][4]  2 KB (ends 38912)
  // epilogue aliases (valid after the final K-iter mid-barrier):
  float* rowP   = (float*)smem;              // [128][18]  9216 B
  float* rowN   = (float*)(smem + 9216);     // [128][18]  (ends 18432 < 32768)

  // XCD-aware swizzle (2080 % 8 == 0, bijective) then upper-tri decode
  int t0 = blockIdx.x;
  int t = (t0 & 7) * (NTILES / 8) + (t0 >> 3);
  int bi = (int)((129.0f - sqrtf(16641.0f - 8.0f * (float)t)) * 0.5f);
  if (bi < 0) bi = 0;
  while (bi > 0 && tri_off(bi) > t) --bi;
  while (tri_off(bi + 1) <= t) ++bi;
  int bj = bi + (t - tri_off(bi));
  int brow = bi * BM, bcol = bj * BM;
  bool diag_blk = (bi == bj);

  int tid = threadIdx.x;
  int wid = tid >> 6, lane = tid & 63;
  int hi = lane >> 4, lo = lane & 15;

  if (tid < BM) {
    s_sq_r[tid] = sqn[brow + tid];
    s_lb_r[tid] = lab[brow + tid];
    s_sq_c[tid] = sqn[bcol + tid];
    s_lb_c[tid] = lab[bcol + tid];
  }

  f32x4 acc[2][8];
  #pragma unroll
  for (int a = 0; a < 2; ++a)
    #pragma unroll
    for (int b = 0; b < 8; ++b) acc[a][b] = (f32x4)(0.f);

  // staging lane constants: lane covers row (seg*8 + lane>>3), 16B chunk
  // (lane&7), fetched from global chunk ((lane&7) ^ (row&7)) so that
  // LDS[row][p] = G[row][p ^ (row&7)]  (both-sides swizzle, linear dest)
  int lrow = lane >> 3;
  int lchunk = (lane & 7) ^ lrow;
  size_t lane_goff = (size_t)lrow * DD + lchunk * 8;   // shorts
  const short* gA = fb + (size_t)brow * DD + lane_goff;
  const short* gB = fb + (size_t)bcol * DD + lane_goff;

  // read-side swizzled chunk: want G[row][C], C = ks*4+hi; row&7 == lo&7
  int cs0 = hi ^ (lo & 7);          // ks=0
  int cs1 = cs0 ^ 4;                // ks=1
  int a0r = wid * 32 + lo;

#define STAGE(ktn) do {                                               \
    int kb_ = (ktn) * BK;                                             \
    _Pragma("unroll")                                                 \
    for (int i_ = 0; i_ < 4; ++i_) {                                  \
      int seg_ = wid * 4 + i_;                                        \
      gload16(gA + (size_t)seg_ * 8 * DD + kb_, &As[seg_ * 512]);     \
      gload16(gB + (size_t)seg_ * 8 * DD + kb_, &Bs[seg_ * 512]);     \
    }                                                                 \
  } while (0)

  STAGE(0);   // prologue

  for (int kt = 0; kt < NKT; ++kt) {
    __syncthreads();   // drains STAGE(kt) (vmcnt0) + prior reads done
    // ks=0 fragments + MFMA
    s16x8 a0 = *(const s16x8*)&As[a0r * 64 + cs0 * 8];
    s16x8 a1 = *(const s16x8*)&As[(a0r + 16) * 64 + cs0 * 8];
    s16x8 bfr[8];
    #pragma unroll
    for (int fc = 0; fc < 8; ++fc)
      bfr[fc] = *(const s16x8*)&Bs[(fc * 16 + lo) * 64 + cs0 * 8];
    #pragma unroll
    for (int fc = 0; fc < 8; ++fc) {
      acc[0][fc] = __builtin_amdgcn_mfma_f32_16x16x32_bf16(a0, bfr[fc], acc[0][fc], 0, 0, 0);
      acc[1][fc] = __builtin_amdgcn_mfma_f32_16x16x32_bf16(a1, bfr[fc], acc[1][fc], 0, 0, 0);
    }
    // ks=1 fragments
    s16x8 c0 = *(const s16x8*)&As[a0r * 64 + cs1 * 8];
    s16x8 c1 = *(const s16x8*)&As[(a0r + 16) * 64 + cs1 * 8];
    s16x8 dfr[8];
    #pragma unroll
    for (int fc = 0; fc < 8; ++fc)
      dfr[fc] = *(const s16x8*)&Bs[(fc * 16 + lo) * 64 + cs1 * 8];
    __syncthreads();   // all waves done reading (lgkm; vmcnt already 0)
    if (kt + 1 < NKT) STAGE(kt + 1);       // overwrite OK; drains next iter
    __builtin_amdgcn_sched_barrier(0);     // keep STAGE above the MFMA cluster
    #pragma unroll
    for (int fc = 0; fc < 8; ++fc) {
      acc[0][fc] = __builtin_amdgcn_mfma_f32_16x16x32_bf16(c0, dfr[fc], acc[0][fc], 0, 0, 0);
      acc[1][fc] = __builtin_amdgcn_mfma_f32_16x16x32_bf16(c1, dfr[fc], acc[1][fc], 0, 0, 0);
    }
  }
#undef STAGE
  // NOTE: the kt=NKT-1 iteration's mid __syncthreads guarantees every
  // wave's LDS reads of As/Bs are complete -> rowP/rowN aliasing is safe.

  // Epilogue: SQUARED distances (unclamped; finalize clamps) + masked
  // max/min, templated on diagonal. Row partials scatter to LDS.
  const float FINF = __int_as_float(0x7f800000);
  auto epilogue = [&](auto diag_c) {
    constexpr bool DIAG = decltype(diag_c)::value;
    float cvp[8], cvn[8];
    #pragma unroll
    for (int fc = 0; fc < 8; ++fc) { cvp[fc] = 0.f; cvn[fc] = FINF; }

    #pragma unroll
    for (int fr = 0; fr < 2; ++fr) {
      #pragma unroll
      for (int rg = 0; rg < 4; ++rg) {
        int rt = wid * 32 + fr * 16 + hi * 4 + rg;
        float sqi = s_sq_r[rt];
        int   li  = s_lb_r[rt];
        float vp = 0.f, vn = FINF;
        #pragma unroll
        for (int fc = 0; fc < 8; ++fc) {
          int ct = fc * 16 + lo;
          float g = acc[fr][fc][rg];
          float v = sqi + s_sq_c[ct] - 2.0f * g;          // squared dist (unclamped)
          if constexpr (DIAG) { if (rt == ct) v = 0.f; }  // diagonal
          bool same = (li == s_lb_c[ct]);
          if (same) {
            vp = fmaxf(vp, v);
            cvp[fc] = fmaxf(cvp[fc], v);
          } else {
            vn = fminf(vn, v);
            cvn[fc] = fminf(cvn[fc], v);
          }
        }
        // scatter this (row, lo) partial; reduce after the barrier
        rowP[rt * 18 + lo] = vp;
        rowN[rt * 18 + lo] = vn;
      }
    }
    // column-side: combine across hi groups in-wave, write [ct][wid] partials
    #pragma unroll
    for (int fc = 0; fc < 8; ++fc) {
      #pragma unroll
      for (int m = 16; m < 64; m <<= 1) {
        cvp[fc] = fmaxf(cvp[fc], __shfl_xor(cvp[fc], m));
        cvn[fc] = fminf(cvn[fc], __shfl_xor(cvn[fc], m));
      }
      if (hi == 0) {
        int ct = fc * 16 + lo;
        colP[ct * 4 + wid] = cvp[fc];
        colN[ct * 4 + wid] = cvn[fc];
      }
    }
    __syncthreads();
    if (tid < BM) {
      // row reduce: 16 contiguous floats, 4 x b128
      f32x4 p0 = *(const f32x4*)&rowP[tid * 18 + 0];
      f32x4 p1 = *(const f32x4*)&rowP[tid * 18 + 4];
      f32x4 p2 = *(const f32x4*)&rowP[tid * 18 + 8];
      f32x4 p3 = *(const f32x4*)&rowP[tid * 18 + 12];
      f32x4 n0 = *(const f32x4*)&rowN[tid * 18 + 0];
      f32x4 n1 = *(const f32x4*)&rowN[tid * 18 + 4];
      f32x4 n2 = *(const f32x4*)&rowN[tid * 18 + 8];
      f32x4 n3 = *(const f32x4*)&rowN[tid * 18 + 12];
      f32x4 pm = __builtin_elementwise_max(__builtin_elementwise_max(p0, p1),
                                           __builtin_elementwise_max(p2, p3));
      f32x4 nm = __builtin_elementwise_min(__builtin_elementwise_min(n0, n1),
                                           __builtin_elementwise_min(n2, n3));
      float p = fmaxf(fmaxf(pm[0], pm[1]), fmaxf(pm[2], pm[3]));
      float n = fminf(fminf(nm[0], nm[1]), fminf(nm[2], nm[3]));
      int gi = brow + tid;
      atomicMax((int*)&pmax[gi], __float_as_int(p));
      atomicMin((int*)&nmin[gi], __float_as_int(n));
      // col reduce: 4 partials, 1 x b128 each
      f32x4 cp = *(const f32x4*)&colP[tid * 4];
      f32x4 cn = *(const f32x4*)&colN[tid * 4];
      float pc = fmaxf(fmaxf(cp[0], cp[1]), fmaxf(cp[2], cp[3]));
      float nc = fminf(fminf(cn[0], cn[1]), fminf(cn[2], cn[3]));
      int gj = bcol + tid;
      atomicMax((int*)&pmax[gj], __float_as_int(pc));
      atomicMin((int*)&nmin[gj], __float_as_int(nc));
    }
  };
  if (diag_blk) epilogue(BoolC<true>{});
  else          epilogue(BoolC<false>{});
}

// Atomic-sign correctness: pmax candidates >= 0 (0-init) -> int-atomicMax
// order-correct. nmin candidates may be tiny-negative (cancellation);
// int-atomicMin ranks negatives below non-negatives, finalize clamps the
// winner to 0 == reference's clamped min.
__global__ __launch_bounds__(256) void finalize_kernel(
    const float* __restrict__ pmax, const float* __restrict__ nmin,
    float* __restrict__ out) {
  int i = blockIdx.x * blockDim.x + threadIdx.x;
  if (i < NN) {
    const float FINF = __int_as_float(0x7f800000);
    float p = fmaxf(pmax[i], 0.f);
    float n = nmin[i];
    if (n == FINF) n = p;       // empty-negative fallback: axis_max == pmax
    n = fmaxf(n, 0.f);
    out[2 * i]     = sqrtf(p);
    out[2 * i + 1] = sqrtf(n);
  }
}

extern "C" void kernel_launch(void* const* d_in, const int* in_sizes, int n_in,
                              void* d_out, int out_size, void* d_ws, size_t ws_size,
                              hipStream_t stream) {
  const float* feat = (const float*)d_in[0];
  const int*   lab  = (const int*)d_in[1];
  float* out = (float*)d_out;

  char* ws = (char*)d_ws;
  short* fb   = (short*)ws;                                  // 8192*512*2 = 8388608 B
  float* sqn  = (float*)(ws + 8388608);                      // 32768 B
  float* pmax = (float*)(ws + 8388608 + 32768);              // 32768 B
  float* nmin = (float*)(ws + 8388608 + 2 * 32768);          // 32768 B

  prep_kernel<<<NN / 4, 256, 0, stream>>>(feat, fb, sqn, pmax, nmin);
  tile_kernel<<<NTILES, 256, 0, stream>>>(fb, sqn, lab, pmax, nmin);
  finalize_kernel<<<(NN + 255) / 256, 256, 0, stream>>>(pmax, nmin, out);
}